// Round 4
// baseline (53.118 us; speedup 1.0000x reference)
//
#include <hip/hip_runtime.h>

#define GB 64
#define GN 128
#define F_OBS 64
#define F_TOT 80
#define NTHREADS 1024
#define NWAVES (NTHREADS / 64)
#define IPT 16   // i-rows per thread

// One block per batch (grid=64, 16 waves). Thread (it, j): j = column (lane),
// it = i-group, handles i in [IPT*it, IPT*it+IPT).
//
// Round-3 lessons baked in:
//  * it via readfirstlane -> rowi/w loads are provably wave-uniform ->
//    s_load_dwordx4 (scalar cache), not per-lane vector loads.
//  * k-OUTER loop: only one float4 of my own row (hv) is live at a time and
//    acc[16] carries the partials -> ~55 VGPR demand, so the allocator has
//    no pressure reason to rematerialize global loads in the hot loop
//    (rounds 1-3 showed VGPR_Count=52 < the 64 needed for a resident row:
//    the own-row was being re-fetched from L1 every MAC).
//  * probs reduced intra-block only, fixed order -> deterministic, and no
//    cross-block fences/atomics (round-2's 7x regression).
__global__ __launch_bounds__(NTHREADS) void glcn_one(
    const float* __restrict__ h, const float* __restrict__ w,
    float* __restrict__ Aout, float* __restrict__ probs) {
  const int b = blockIdx.x;
  const int j = threadIdx.x & (GN - 1);
  const int it = __builtin_amdgcn_readfirstlane(threadIdx.x >> 7);  // 0..7

  const float* rowj = h + ((size_t)(b * GN + j)) * F_TOT;          // per-lane
  const float* rows = h + ((size_t)(b * GN + it * IPT)) * F_TOT;   // scalar

  float acc[IPT];
#pragma unroll
  for (int ii = 0; ii < IPT; ++ii) acc[ii] = 0.f;

#pragma unroll 4
  for (int kq = 0; kq < F_OBS / 4; ++kq) {
    const float4 hv = *reinterpret_cast<const float4*>(rowj + 4 * kq);
    const float4 wv = *reinterpret_cast<const float4*>(w + 4 * kq);  // scalar
#pragma unroll
    for (int ii = 0; ii < IPT; ++ii) {
      const float* ri = rows + ii * F_TOT + 4 * kq;   // scalar dwordx4
      // exact k-order accumulation per row; abs folds into fma input mod
      acc[ii] = fmaf(wv.x, fabsf(hv.x - ri[0]), acc[ii]);
      acc[ii] = fmaf(wv.y, fabsf(hv.y - ri[1]), acc[ii]);
      acc[ii] = fmaf(wv.z, fabsf(hv.z - ri[2]), acc[ii]);
      acc[ii] = fmaf(wv.w, fabsf(hv.w - ri[3]), acc[ii]);
    }
  }

  // Epilogue: sigmoid -> hard threshold -> log-likelihood + coalesced stores.
  float logsum = 0.f;
  float* Abase = Aout + (size_t)b * GN * GN;
#pragma unroll
  for (int ii = 0; ii < IPT; ++ii) {
    const int i = it * IPT + ii;
    const float ysoft = 1.f / (1.f + __expf(-acc[ii]));
    float Aval = (ysoft > 0.5f) ? 1.f : 0.f;
    const float sel = (Aval != 0.f) ? ysoft : (1.f - ysoft);
    const float lt = __logf(sel + 1e-8f);
    if (i == j) Aval = 1.f;     // diagonal: forced 1, excluded from log-sum
    else        logsum += lt;
    Abase[(size_t)i * GN + j] = Aval;   // lanes = consecutive j: coalesced
  }

  // Deterministic intra-block reduction: wave shfl tree, then thread 0 sums
  // the 16 wave partials in fixed index order.
#pragma unroll
  for (int off = 32; off > 0; off >>= 1)
    logsum += __shfl_down(logsum, off, 64);
  __shared__ float red[NWAVES];
  const int lane = threadIdx.x & 63;
  const int wid  = threadIdx.x >> 6;
  if (lane == 0) red[wid] = logsum;
  __syncthreads();
  if (threadIdx.x == 0) {
    float s = 0.f;
#pragma unroll
    for (int q = 0; q < NWAVES; ++q) s += red[q];
    probs[b] = s;
  }
}

extern "C" void kernel_launch(void* const* d_in, const int* in_sizes, int n_in,
                              void* d_out, int out_size, void* d_ws, size_t ws_size,
                              hipStream_t stream) {
  const float* h = (const float*)d_in[0];   // [64,128,80] f32
  const float* w = (const float*)d_in[1];   // [64,1] f32
  float* Aout  = (float*)d_out;                       // [64,128,128]
  float* probs = Aout + (size_t)GB * GN * GN;         // [64]

  glcn_one<<<GB, NTHREADS, 0, stream>>>(h, w, Aout, probs);
}

// Round 5
// 30.043 us; speedup vs baseline: 1.7681x; 1.7681x over previous
//
#include <hip/hip_runtime.h>

#define GB 64
#define GN 128
#define F_OBS 64
#define F_TOT 80
#define ISPLIT 32
#define IPB (GN / ISPLIT)   // 4 i-rows per block

// Wide grid: 2048 blocks (64 batches x 32 i-splits) x 128 threads = 8
// blocks/CU across all 256 CUs. Thread = column j; block owns 4 i-rows.
//
// Lessons baked in:
//  * R2: NO cross-block ordering (fences/acq-rel/last-block) -- a single
//    relaxed atomicAdd of the block partial is cheap (64 destinations,
//    2048 adds); probs zeroed by a 256B hipMemsetAsync.
//  * R3/R4: one-block-per-batch caps the chip at 25% issue width -- use the
//    full grid. rows/w derive from blockIdx only -> provably wave-uniform ->
//    s_load (scalar cache, separate pipe from VALU).
//  * R4: k-outer + acc[IPB] keeps live state ~tiny (no remat of the own-row:
//    full unroll lets the scheduler hoist all 16 hv float4 loads early).
__global__ __launch_bounds__(128) void glcn_fused(
    const float* __restrict__ h, const float* __restrict__ w,
    float* __restrict__ Aout, float* __restrict__ probs) {
  const int blk = blockIdx.x;
  const int b  = blk >> 5;                    // / ISPLIT
  const int is = (blk & (ISPLIT - 1)) * IPB;  // block-uniform
  const int j  = threadIdx.x;                 // 0..127

  const float* rowj = h + ((size_t)(b * GN + j)) * F_TOT;    // per-lane
  const float* rows = h + ((size_t)(b * GN + is)) * F_TOT;   // uniform->s_load

  float acc[IPB];
#pragma unroll
  for (int ii = 0; ii < IPB; ++ii) acc[ii] = 0.f;

#pragma unroll
  for (int kq = 0; kq < F_OBS / 4; ++kq) {
    const float4 hv = *reinterpret_cast<const float4*>(rowj + 4 * kq);
    const float4 wv = *reinterpret_cast<const float4*>(w + 4 * kq);  // scalar
#pragma unroll
    for (int ii = 0; ii < IPB; ++ii) {
      const float* ri = rows + ii * F_TOT + 4 * kq;   // scalar dwordx4
      acc[ii] = fmaf(wv.x, fabsf(hv.x - ri[0]), acc[ii]);
      acc[ii] = fmaf(wv.y, fabsf(hv.y - ri[1]), acc[ii]);
      acc[ii] = fmaf(wv.z, fabsf(hv.z - ri[2]), acc[ii]);
      acc[ii] = fmaf(wv.w, fabsf(hv.w - ri[3]), acc[ii]);
    }
  }

  // Epilogue. sigmoid(x)>0.5 <=> x>0; selected = max(y,1-y) = sigmoid(|x|).
  float logsum = 0.f;
  float* Abase = Aout + (size_t)b * GN * GN;
#pragma unroll
  for (int ii = 0; ii < IPB; ++ii) {
    const int i = is + ii;
    const float x = acc[ii];
    const float sel = 1.f / (1.f + __expf(-fabsf(x)));
    const float lt  = __logf(sel + 1e-8f);
    float Aval = (x > 0.f) ? 1.f : 0.f;
    if (i == j) Aval = 1.f;     // diagonal: forced 1, excluded from log-sum
    else        logsum += lt;
    Abase[(size_t)i * GN + j] = Aval;   // lanes = consecutive j: coalesced
  }

  // Deterministic intra-block reduction, then ONE relaxed atomic per block.
#pragma unroll
  for (int off = 32; off > 0; off >>= 1)
    logsum += __shfl_down(logsum, off, 64);
  __shared__ float red[2];
  const int lane = threadIdx.x & 63;
  const int wid  = threadIdx.x >> 6;
  if (lane == 0) red[wid] = logsum;
  __syncthreads();
  if (threadIdx.x == 0) atomicAdd(&probs[b], red[0] + red[1]);
}

extern "C" void kernel_launch(void* const* d_in, const int* in_sizes, int n_in,
                              void* d_out, int out_size, void* d_ws, size_t ws_size,
                              hipStream_t stream) {
  const float* h = (const float*)d_in[0];   // [64,128,80] f32
  const float* w = (const float*)d_in[1];   // [64,1] f32
  float* Aout  = (float*)d_out;                       // [64,128,128]
  float* probs = Aout + (size_t)GB * GN * GN;         // [64]

  hipMemsetAsync(probs, 0, GB * sizeof(float), stream);  // 256 B, capture-safe
  glcn_fused<<<GB * ISPLIT, 128, 0, stream>>>(h, w, Aout, probs);
}

// Round 6
// 18.870 us; speedup vs baseline: 2.8149x; 1.5921x over previous
//
#include <hip/hip_runtime.h>

#define GB 64
#define GN 128
#define F_OBS 64
#define F_TOT 80
#define ISPLIT 16
#define IPB (GN / ISPLIT)   // 8 i-rows per block

// R1's proven dispatch structure (best so far: 21.5us) with R5's improved
// inner loop. 1024 blocks (64 batches x 16 i-splits) x 128 threads; thread =
// column j; block owns 8 i-rows. part[] plain stores + tiny reduce kernel:
// NO memset node, NO atomics (R5's two regression suspects), NO cross-block
// ordering (R2's 7x regression).
//
// Inner loop: k-outer, acc[8] partials; `is` derives only from blockIdx ->
// rowi/w loads are provably wave-uniform -> s_load_dwordx4 on the scalar
// pipe. unroll 4 keeps only 4 own-row float4 chunks live (~16 VGPR) so the
// allocator has no pressure reason to rematerialize per-lane loads (R1's
// main showed VGPR=52: own-row was re-fetched from L1 inside the MAC loop).
__global__ __launch_bounds__(128) void glcn_main(
    const float* __restrict__ h, const float* __restrict__ w,
    float* __restrict__ Aout, float* __restrict__ part) {
  const int blk = blockIdx.x;
  const int b  = blk >> 4;                    // / ISPLIT
  const int is = (blk & (ISPLIT - 1)) * IPB;  // block-uniform
  const int j  = threadIdx.x;                 // 0..127

  const float* rowj = h + ((size_t)(b * GN + j)) * F_TOT;    // per-lane
  const float* rows = h + ((size_t)(b * GN + is)) * F_TOT;   // uniform->s_load

  float acc[IPB];
#pragma unroll
  for (int ii = 0; ii < IPB; ++ii) acc[ii] = 0.f;

#pragma unroll 4
  for (int kq = 0; kq < F_OBS / 4; ++kq) {
    const float4 hv = *reinterpret_cast<const float4*>(rowj + 4 * kq);
    const float4 wv = *reinterpret_cast<const float4*>(w + 4 * kq);  // scalar
#pragma unroll
    for (int ii = 0; ii < IPB; ++ii) {
      const float* ri = rows + ii * F_TOT + 4 * kq;   // scalar dwordx4
      acc[ii] = fmaf(wv.x, fabsf(hv.x - ri[0]), acc[ii]);
      acc[ii] = fmaf(wv.y, fabsf(hv.y - ri[1]), acc[ii]);
      acc[ii] = fmaf(wv.z, fabsf(hv.z - ri[2]), acc[ii]);
      acc[ii] = fmaf(wv.w, fabsf(hv.w - ri[3]), acc[ii]);
    }
  }

  // Epilogue. sigmoid(x)>0.5 <=> x>0; selected = A?y:(1-y) = sigmoid(|x|)
  // (x>0: y=sig(|x|); x<=0: 1-y=sig(-x)=sig(|x|)). Diagonal x==0 exactly.
  float logsum = 0.f;
  float* Abase = Aout + (size_t)b * GN * GN;
#pragma unroll
  for (int ii = 0; ii < IPB; ++ii) {
    const int i = is + ii;
    const float x = acc[ii];
    const float sel = 1.f / (1.f + __expf(-fabsf(x)));
    const float lt  = __logf(sel + 1e-8f);
    float Aval = (x > 0.f) ? 1.f : 0.f;
    if (i == j) Aval = 1.f;     // diagonal: forced 1, excluded from log-sum
    else        logsum += lt;
    Abase[(size_t)i * GN + j] = Aval;   // lanes = consecutive j: coalesced
  }

  // Deterministic intra-block reduction (fixed shuffle-tree order).
#pragma unroll
  for (int off = 32; off > 0; off >>= 1)
    logsum += __shfl_down(logsum, off, 64);
  __shared__ float red[2];
  const int lane = threadIdx.x & 63;
  const int wid  = threadIdx.x >> 6;
  if (lane == 0) red[wid] = logsum;
  __syncthreads();
  if (threadIdx.x == 0) part[blk] = red[0] + red[1];
}

// probs[b] = sum of the 16 block partials, fixed order (deterministic).
__global__ __launch_bounds__(64) void glcn_reduce(
    const float* __restrict__ part, float* __restrict__ probs) {
  const int b = threadIdx.x;
  float s = 0.f;
#pragma unroll
  for (int q = 0; q < ISPLIT; ++q) s += part[b * ISPLIT + q];
  probs[b] = s;
}

extern "C" void kernel_launch(void* const* d_in, const int* in_sizes, int n_in,
                              void* d_out, int out_size, void* d_ws, size_t ws_size,
                              hipStream_t stream) {
  const float* h = (const float*)d_in[0];   // [64,128,80] f32
  const float* w = (const float*)d_in[1];   // [64,1] f32
  float* Aout  = (float*)d_out;                       // [64,128,128]
  float* probs = Aout + (size_t)GB * GN * GN;         // [64]
  float* part  = (float*)d_ws;                        // GB*ISPLIT floats

  glcn_main<<<GB * ISPLIT, 128, 0, stream>>>(h, w, Aout, part);
  glcn_reduce<<<1, 64, 0, stream>>>(part, probs);
}